// Round 2
// baseline (7433.131 us; speedup 1.0000x reference)
//
#include <hip/hip_runtime.h>
#include <hip/hip_bf16.h>
#include <math.h>

// ---------------------------------------------------------------------------
// Gemma audio layer: chunked local attention w/ Transformer-XL rel-shift.
// Round 1: fp32 baseline, SEGMENTED so workspace fits any ws_size >= ~6.3 MB.
// Segment = (batch b, G consecutive chunks). Buffers per segment:
//   q_seg[G*128], k_seg[(G+1)*128], v_seg[(G+1)*128] (128-row front halo,
//   zero-filled at batch start = reference's zero pad), attn_seg[G*128].
// ---------------------------------------------------------------------------

#define NH_    12
#define HD_    128
#define H_     1536
#define B_     4
#define S_     4096
#define CHUNK_ 128
#define PAST_  127
#define CTX_   255
#define NB_    32

static constexpr float Q_SCALE_F = (float)(0.08838834764831845 / 0.6931471805599453); // HD^-0.5 / ln2
static constexpr float K_SCALE_F = (float)(1.3132616875182228 / 0.6931471805599453);  // log1p(e) / ln2
#define SOFTCAP_ 50.0f

__device__ __forceinline__ float dot4f(float4 a, float4 b) {
    return fmaf(a.x, b.x, fmaf(a.y, b.y, fmaf(a.z, b.z, a.w * b.w)));
}

// ---------------------------------------------------------------------------
// C[M,N] = A[M,K] @ B[N,K]^T   (row-major, K multiple of 8, N multiple of 128)
// Rows gr < first_valid or gr >= M read as zero (zero-pad semantics); all rows
// < M are stored. mode: 0 none, 1 q-scale (per-col softplus), 2 k-scale.
// ---------------------------------------------------------------------------
#define BM 128
#define BN 128
#define BK 8

__global__ __launch_bounds__(256)
void sgemm_nt(const float* __restrict__ A, const float* __restrict__ Bw,
              float* __restrict__ C, int M, int N, int K,
              int first_valid, int mode, const float* __restrict__ pds)
{
    __shared__ float a_s[BK][BM + 4];
    __shared__ float b_s[BK][BN + 4];

    const int bm = blockIdx.y * BM;
    const int bn = blockIdx.x * BN;
    const int tid = threadIdx.x;
    const int tm = (tid >> 4) << 3;
    const int tn = (tid & 15) << 3;
    const int lr = tid >> 1;          // staging row within tile
    const int lk = (tid & 1) << 2;    // staging k offset 0/4

    float acc[8][8];
#pragma unroll
    for (int i = 0; i < 8; ++i)
#pragma unroll
        for (int j = 0; j < 8; ++j) acc[i][j] = 0.f;

    for (int k0 = 0; k0 < K; k0 += BK) {
        const int gr = bm + lr;
        float4 av = make_float4(0.f, 0.f, 0.f, 0.f);
        if (gr >= first_valid && gr < M)
            av = *(const float4*)(A + (size_t)gr * K + k0 + lk);
        const int gn = bn + lr;
        float4 bv = make_float4(0.f, 0.f, 0.f, 0.f);
        if (gn < N) bv = *(const float4*)(Bw + (size_t)gn * K + k0 + lk);

        __syncthreads();   // protect previous iter's fragment reads
        a_s[lk + 0][lr] = av.x; a_s[lk + 1][lr] = av.y;
        a_s[lk + 2][lr] = av.z; a_s[lk + 3][lr] = av.w;
        b_s[lk + 0][lr] = bv.x; b_s[lk + 1][lr] = bv.y;
        b_s[lk + 2][lr] = bv.z; b_s[lk + 3][lr] = bv.w;
        __syncthreads();

#pragma unroll
        for (int kk = 0; kk < BK; ++kk) {
            float4 a0 = *(const float4*)&a_s[kk][tm];
            float4 a1 = *(const float4*)&a_s[kk][tm + 4];
            float4 b0 = *(const float4*)&b_s[kk][tn];
            float4 b1 = *(const float4*)&b_s[kk][tn + 4];
            float af[8] = {a0.x, a0.y, a0.z, a0.w, a1.x, a1.y, a1.z, a1.w};
            float bf[8] = {b0.x, b0.y, b0.z, b0.w, b1.x, b1.y, b1.z, b1.w};
#pragma unroll
            for (int i = 0; i < 8; ++i)
#pragma unroll
                for (int j = 0; j < 8; ++j)
                    acc[i][j] = fmaf(af[i], bf[j], acc[i][j]);
        }
    }

    float scale[8];
#pragma unroll
    for (int j = 0; j < 8; ++j) {
        float s = 1.f;
        if (mode == 1) {
            int col = bn + tn + j;
            float x = pds[col & (HD_ - 1)];
            s = Q_SCALE_F * log1pf(expf(x));
        } else if (mode == 2) {
            s = K_SCALE_F;
        }
        scale[j] = s;
    }
#pragma unroll
    for (int i = 0; i < 8; ++i) {
        const int row = bm + tm + i;
        if (row >= M) continue;
        float* cp = C + (size_t)row * N + bn + tn;
        *(float4*)cp = make_float4(acc[i][0] * scale[0], acc[i][1] * scale[1],
                                   acc[i][2] * scale[2], acc[i][3] * scale[3]);
        *(float4*)(cp + 4) = make_float4(acc[i][4] * scale[4], acc[i][5] * scale[5],
                                         acc[i][6] * scale[6], acc[i][7] * scale[7]);
    }
}

// ---------------------------------------------------------------------------
// Fused attention on segment-local buffers.
// Block = (rowgroup rg of 16 q-rows, head h, local chunk ln).
//   Phase A: G[17][256] = q(17 rows incl. halo) @ relk^T  (col 255 = 0 pad)
//   Phase B: ac = q @ k_ctx^T; logits = softcap*tanh((ac + shift(G))/softcap)
//   softmax over x in [0,255); Phase C: out = W @ v_ctx
// rel_shift: bd[c,x] = G[c][x-c] if x>=c else G[c-1][x-c+256]
// k_seg/v_seg have a 128-row front halo: ctx pos pp -> seg row ln*128+1+pp.
// ---------------------------------------------------------------------------
#define ROWS_ 16

__global__ __launch_bounds__(256)
void attn_fused(const float* __restrict__ q_seg, const float* __restrict__ k_seg,
                const float* __restrict__ v_seg, const float* __restrict__ relk,
                float* __restrict__ attn_seg)
{
    const int rg = blockIdx.x;            // 0..7
    const int h  = blockIdx.y;            // 0..11
    const int ln = blockIdx.z;            // local chunk in segment
    const int tid = threadIdx.x;
    const int c0 = rg * ROWS_;

    // LDS (63776 B): p_s[16][260] persistent | region reused:
    //   A/B: q_s[17][132] | g_s[17][260] | kst[256][20]
    //   C  : v_s[64][140]
    __shared__ __align__(16) char smem_raw[63776];
    float* p_s = (float*)smem_raw;
    char*  region = smem_raw + 16 * 260 * 4;
    float* q_s = (float*)region;
    float* g_s = (float*)(region + 17 * 132 * 4);
    float* kst = (float*)(region + 17 * 132 * 4 + 17 * 260 * 4);
    float* v_s = (float*)region;

    // ---- stage q rows c0-1 .. c0+15 (seg row ln*128 + c; row < 0 -> 0)
    for (int idx = tid; idx < 17 * HD_; idx += 256) {
        const int r = idx >> 7, d = idx & 127;
        const int qr = ln * CHUNK_ + c0 - 1 + r;
        float val = 0.f;
        if (qr >= 0) val = q_seg[(size_t)qr * H_ + h * HD_ + d];
        q_s[r * 132 + d] = val;
    }
    __syncthreads();

    // ---- Phase A: G rows (17) x cols (256); thread owns col p = tid
    {
        const int p = tid;
        float gacc[17];
#pragma unroll
        for (int r = 0; r < 17; ++r) gacc[r] = 0.f;

        for (int dc = 0; dc < HD_; dc += 16) {
            __syncthreads();
            for (int idx = tid; idx < 256 * 16; idx += 256) {
                const int pp = idx >> 4, dd = idx & 15;
                float val = 0.f;
                if (pp < CTX_) val = relk[(size_t)pp * H_ + h * HD_ + dc + dd];
                kst[pp * 20 + dd] = val;
            }
            __syncthreads();
            float4 rk0 = *(const float4*)&kst[p * 20 + 0];
            float4 rk1 = *(const float4*)&kst[p * 20 + 4];
            float4 rk2 = *(const float4*)&kst[p * 20 + 8];
            float4 rk3 = *(const float4*)&kst[p * 20 + 12];
#pragma unroll
            for (int r = 0; r < 17; ++r) {
                const float* qr = &q_s[r * 132 + dc];
                float4 qa = *(const float4*)(qr + 0);
                float4 qb = *(const float4*)(qr + 4);
                float4 qc = *(const float4*)(qr + 8);
                float4 qd = *(const float4*)(qr + 12);
                gacc[r] += dot4f(qa, rk0) + dot4f(qb, rk1) +
                           dot4f(qc, rk2) + dot4f(qd, rk3);
            }
        }
#pragma unroll
        for (int r = 0; r < 17; ++r) g_s[r * 260 + p] = gacc[r];
    }

    // ---- Phase B: ac + shift-combine + softcap; thread owns col x = tid
    {
        const int x = tid;
        float acc[ROWS_];
#pragma unroll
        for (int r = 0; r < ROWS_; ++r) acc[r] = 0.f;

        for (int dc = 0; dc < HD_; dc += 16) {
            __syncthreads();
            for (int idx = tid; idx < 256 * 16; idx += 256) {
                const int pp = idx >> 4, dd = idx & 15;
                float val = 0.f;
                if (pp < CTX_) {
                    const int kr = ln * CHUNK_ + 1 + pp;  // halo offset
                    val = k_seg[(size_t)kr * H_ + h * HD_ + dc + dd];
                }
                kst[pp * 20 + dd] = val;
            }
            __syncthreads();
            float4 rk0 = *(const float4*)&kst[x * 20 + 0];
            float4 rk1 = *(const float4*)&kst[x * 20 + 4];
            float4 rk2 = *(const float4*)&kst[x * 20 + 8];
            float4 rk3 = *(const float4*)&kst[x * 20 + 12];
#pragma unroll
            for (int r = 0; r < ROWS_; ++r) {
                const float* qr = &q_s[(r + 1) * 132 + dc];
                float4 qa = *(const float4*)(qr + 0);
                float4 qb = *(const float4*)(qr + 4);
                float4 qc = *(const float4*)(qr + 8);
                float4 qd = *(const float4*)(qr + 12);
                acc[r] += dot4f(qa, rk0) + dot4f(qb, rk1) +
                          dot4f(qc, rk2) + dot4f(qd, rk3);
            }
        }
        __syncthreads();  // g_s fully written; kst reads done

#pragma unroll
        for (int r = 0; r < ROWS_; ++r) {
            float l;
            if (x == 255) {
                l = -1e30f;
            } else {
                const int c = c0 + r;
                const float bd = (x >= c) ? g_s[(r + 1) * 260 + (x - c)]
                                          : g_s[r * 260 + (x - c + 256)];
                l = SOFTCAP_ * tanhf((acc[r] + bd) * (1.f / SOFTCAP_));
            }
            p_s[r * 260 + x] = l;
        }
    }
    __syncthreads();

    // ---- softmax per row (col 255 = -1e30 -> weight 0)
    {
        const int r = tid >> 4;
        const int i = tid & 15;
        float m = -1e30f;
#pragma unroll
        for (int t = 0; t < 16; ++t)
            m = fmaxf(m, p_s[r * 260 + i + 16 * t]);
#pragma unroll
        for (int off = 1; off < 16; off <<= 1)
            m = fmaxf(m, __shfl_xor(m, off, 16));
        float pv[16];
        float sum = 0.f;
#pragma unroll
        for (int t = 0; t < 16; ++t) {
            const float e = __expf(p_s[r * 260 + i + 16 * t] - m);
            pv[t] = e;
            sum += e;
        }
#pragma unroll
        for (int off = 1; off < 16; off <<= 1)
            sum += __shfl_xor(sum, off, 16);
        const float inv = 1.f / sum;
#pragma unroll
        for (int t = 0; t < 16; ++t)
            p_s[r * 260 + i + 16 * t] = pv[t] * inv;
    }
    __syncthreads();

    // ---- Phase C: PV. thread = (row r, d-group dg)
    {
        const int r  = tid >> 4;
        const int dg = tid & 15;
        float4 o0 = make_float4(0.f, 0.f, 0.f, 0.f);
        float4 o1 = make_float4(0.f, 0.f, 0.f, 0.f);

        for (int xc = 0; xc < 4; ++xc) {
            __syncthreads();  // protect q_s/g_s (first iter) / prev v_s reads
            for (int idx = tid; idx < 64 * HD_; idx += 256) {
                const int xl = idx >> 7, dd = idx & 127;
                const int xg = xc * 64 + xl;
                float val = 0.f;
                if (xg < CTX_) {
                    const int vr = ln * CHUNK_ + 1 + xg;
                    val = v_seg[(size_t)vr * H_ + h * HD_ + dd];
                }
                v_s[xl * 140 + dd] = val;
            }
            __syncthreads();
            for (int xl = 0; xl < 64; ++xl) {
                const float w = p_s[r * 260 + xc * 64 + xl];
                float4 va = *(const float4*)&v_s[xl * 140 + dg * 4];
                float4 vb = *(const float4*)&v_s[xl * 140 + 64 + dg * 4];
                o0.x = fmaf(w, va.x, o0.x); o0.y = fmaf(w, va.y, o0.y);
                o0.z = fmaf(w, va.z, o0.z); o0.w = fmaf(w, va.w, o0.w);
                o1.x = fmaf(w, vb.x, o1.x); o1.y = fmaf(w, vb.y, o1.y);
                o1.z = fmaf(w, vb.z, o1.z); o1.w = fmaf(w, vb.w, o1.w);
            }
        }
        const int row = ln * CHUNK_ + c0 + r;
        float* op = attn_seg + (size_t)row * H_ + h * HD_;
        *(float4*)(op + dg * 4) = o0;
        *(float4*)(op + 64 + dg * 4) = o1;
    }
}

// ---------------------------------------------------------------------------
extern "C" void kernel_launch(void* const* d_in, const int* in_sizes, int n_in,
                              void* d_out, int out_size, void* d_ws, size_t ws_size,
                              hipStream_t stream)
{
    (void)in_sizes; (void)n_in; (void)out_size;

    const float* hs    = (const float*)d_in[0];
    const float* pos   = (const float*)d_in[1];
    const float* Wq    = (const float*)d_in[2];
    const float* Wk    = (const float*)d_in[3];
    const float* Wv    = (const float*)d_in[4];
    const float* Wrel  = (const float*)d_in[5];
    const float* Wpost = (const float*)d_in[6];
    const float* pds   = (const float*)d_in[7];
    float* out = (float*)d_out;

    const size_t CHW = (size_t)CHUNK_ * H_;          // floats per chunk-row-block
    const size_t relk_pad = 256 * (size_t)H_;        // padded relk slab

    // choose largest segment size (chunks) that fits ws_size
    int G = 0;
    const int cand[6] = {32, 16, 8, 4, 2, 1};
    for (int ci = 0; ci < 6; ++ci) {
        const int g = cand[ci];
        const size_t need = (relk_pad + (size_t)(4 * g + 2) * CHW) * sizeof(float);
        if (need <= ws_size) { G = g; break; }
    }
    if (G == 0) return;  // ws_size < ~6.3 MB: cannot run

    float* relkb = (float*)d_ws;
    float* qb    = relkb + relk_pad;
    float* kb    = qb + (size_t)G * CHW;
    float* vb    = kb + (size_t)(G + 1) * CHW;
    float* ab    = vb + (size_t)(G + 1) * CHW;

    dim3 blk(256);

    // rel-k projection (once)
    sgemm_nt<<<dim3(H_ / BN, 2), blk, 0, stream>>>(
        pos, Wrel, relkb, CTX_, H_, H_, 0, 0, nullptr);

    for (int b = 0; b < B_; ++b) {
        for (int n0 = 0; n0 < NB_; n0 += G) {
            const int Mq  = G * CHUNK_;
            const int Mkv = (G + 1) * CHUNK_;
            const float* hq = hs + ((size_t)b * S_ + (size_t)n0 * CHUNK_) * H_;
            const float* hk = hq - CHW;                 // 128-row front halo
            const int fv = (n0 == 0) ? CHUNK_ : 0;      // zero-pad batch front

            sgemm_nt<<<dim3(H_ / BN, Mq / BM), blk, 0, stream>>>(
                hq, Wq, qb, Mq, H_, H_, 0, 1, pds);
            sgemm_nt<<<dim3(H_ / BN, Mkv / BM), blk, 0, stream>>>(
                hk, Wk, kb, Mkv, H_, H_, fv, 2, nullptr);
            sgemm_nt<<<dim3(H_ / BN, Mkv / BM), blk, 0, stream>>>(
                hk, Wv, vb, Mkv, H_, H_, fv, 0, nullptr);

            attn_fused<<<dim3(CHUNK_ / ROWS_, NH_, G), blk, 0, stream>>>(
                qb, kb, vb, relkb, ab);

            sgemm_nt<<<dim3(H_ / BN, Mq / BM), blk, 0, stream>>>(
                ab, Wpost, out + ((size_t)b * S_ + (size_t)n0 * CHUNK_) * H_,
                Mq, H_, H_, 0, 0, nullptr);
        }
    }
}

// Round 3
// 1829.777 us; speedup vs baseline: 4.0623x; 4.0623x over previous
//
#include <hip/hip_runtime.h>
#include <hip/hip_bf16.h>
#include <math.h>

// ---------------------------------------------------------------------------
// Gemma audio layer, round 2: bf16 MFMA everywhere.
//   - weights pre-converted to bf16 with scales baked in (Wq rows *= QS*sp(pds),
//     Wk *= KS)  -> scale-free GEMMs
//   - one fused qkv GEMM (N=4608), m97-style 128x128 MFMA tile, swizzled LDS
//   - attention: 8-wave MFMA kernel per (chunk, head); rel-shift via G in LDS
//   - segmented like round 1 (G chunks/segment) so workspace always fits
// ---------------------------------------------------------------------------

#define NH_    12
#define HD_    128
#define H_     1536
#define B_     4
#define S_     4096
#define CHUNK_ 128
#define CTX_   255
#define NB_    32
#define QKVW_  4608

typedef unsigned short u16;
typedef short bf16x8 __attribute__((ext_vector_type(8)));
typedef float f32x4 __attribute__((ext_vector_type(4)));

static constexpr float Q_SCALE_F = (float)(0.08838834764831845 / 0.6931471805599453);
static constexpr float K_SCALE_F = (float)(1.3132616875182228 / 0.6931471805599453);

__device__ __forceinline__ u16 f2bf(float f) {
    __hip_bfloat16 h = __float2bfloat16(f);
    return __builtin_bit_cast(u16, h);
}
__device__ __forceinline__ float bf2f(u16 u) {
    unsigned int t = ((unsigned int)u) << 16;
    return __builtin_bit_cast(float, t);
}

// ---------------------------------------------------------------------------
// fp32 -> bf16 conversion with optional scaling / zero-fill.
// dst[i] = (i<zero_below || i>=zero_from) ? 0 : scale * src[base+i]
// mode: 0 none, 1 per-row q-scale (QS*softplus(pds[(i/ncols)&127])), 2 K_SCALE
// n, zero_below, zero_from multiples of 4.
// ---------------------------------------------------------------------------
__global__ __launch_bounds__(256)
void conv_bf16(const float* __restrict__ src, long long base,
               u16* __restrict__ dst, long long n,
               long long zero_below, long long zero_from,
               int mode, const float* __restrict__ pds, int ncols)
{
    long long i = ((long long)blockIdx.x * 256 + threadIdx.x) * 4;
    if (i >= n) return;
    float4 v = make_float4(0.f, 0.f, 0.f, 0.f);
    if (i >= zero_below && i < zero_from)
        v = *(const float4*)(src + base + i);
    float s = 1.f;
    if (mode == 1) {
        int row = (int)(i / ncols);
        float x = pds[row & 127];
        float sp = (x > 20.f) ? x : log1pf(__expf(x));
        s = Q_SCALE_F * sp;
    } else if (mode == 2) {
        s = K_SCALE_F;
    }
    u16 o0 = f2bf(v.x * s), o1 = f2bf(v.y * s), o2 = f2bf(v.z * s), o3 = f2bf(v.w * s);
    ushort4 o = make_ushort4(o0, o1, o2, o3);
    *(ushort4*)(dst + i) = o;
}

// ---------------------------------------------------------------------------
// bf16 GEMM  C[M,N] = A[M,K] @ B[N,K]^T  (both row-major bf16, K mult of 32,
// M,N mult of 128). OUTB: 1 -> bf16 C, 0 -> fp32 C.
// 128x128 tile, 4 waves, 16x16x32 MFMA, swizzled LDS (write==read mapping).
// ---------------------------------------------------------------------------
template<int OUTB>
__global__ __launch_bounds__(256)
void gemm_bt(const u16* __restrict__ A, const u16* __restrict__ B,
             void* __restrict__ Cp, int M, int N, int K, int ldc)
{
    __shared__ __align__(16) u16 a_s[128 * 32];
    __shared__ __align__(16) u16 b_s[128 * 32];

    const int tid = threadIdx.x;
    const int w = tid >> 6, l = tid & 63;
    const int lr = l & 15, lg = l >> 4;
    const int bm = blockIdx.y * 128, bn = blockIdx.x * 128;
    const int wr = (w >> 1) * 64, wc = (w & 1) * 64;

    // staging: thread handles slots tid and tid+256 (16B each) of A and B
    int srow[2], skg[2], sphys[2];
#pragma unroll
    for (int i = 0; i < 2; ++i) {
        int s = tid + i * 256;
        int row = s >> 2, kg = s & 3;
        srow[i] = row; skg[i] = kg;
        int pr = row ^ ((row >> 2) & 1);
        int pk = kg ^ (row & 3);
        sphys[i] = pr * 64 + pk * 16;   // byte offset in 8KB tile
    }
    // frag read offsets (bytes), same swizzle
    int a_off[4], b_off[4];
#pragma unroll
    for (int m = 0; m < 4; ++m) {
        int row = wr + m * 16 + lr;
        a_off[m] = (row ^ ((row >> 2) & 1)) * 64 + ((lg ^ (row & 3)) * 16);
        int rowb = wc + m * 16 + lr;
        b_off[m] = (rowb ^ ((rowb >> 2) & 1)) * 64 + ((lg ^ (rowb & 3)) * 16);
    }

    f32x4 acc[4][4];
#pragma unroll
    for (int m = 0; m < 4; ++m)
#pragma unroll
        for (int n = 0; n < 4; ++n) acc[m][n] = (f32x4){0.f, 0.f, 0.f, 0.f};

    int4 areg[2], breg[2];
#pragma unroll
    for (int i = 0; i < 2; ++i) {
        areg[i] = *(const int4*)(A + (size_t)(bm + srow[i]) * K + skg[i] * 8);
        breg[i] = *(const int4*)(B + (size_t)(bn + srow[i]) * K + skg[i] * 8);
    }

    for (int k0 = 0; k0 < K; k0 += 32) {
        __syncthreads();   // previous frag reads done
        *(int4*)((char*)a_s + sphys[0]) = areg[0];
        *(int4*)((char*)a_s + sphys[1]) = areg[1];
        *(int4*)((char*)b_s + sphys[0]) = breg[0];
        *(int4*)((char*)b_s + sphys[1]) = breg[1];
        __syncthreads();
        if (k0 + 32 < K) {
#pragma unroll
            for (int i = 0; i < 2; ++i) {
                areg[i] = *(const int4*)(A + (size_t)(bm + srow[i]) * K + k0 + 32 + skg[i] * 8);
                breg[i] = *(const int4*)(B + (size_t)(bn + srow[i]) * K + k0 + 32 + skg[i] * 8);
            }
        }
        bf16x8 af[4], bfr[4];
#pragma unroll
        for (int m = 0; m < 4; ++m) af[m]  = *(const bf16x8*)((const char*)a_s + a_off[m]);
#pragma unroll
        for (int n = 0; n < 4; ++n) bfr[n] = *(const bf16x8*)((const char*)b_s + b_off[n]);
#pragma unroll
        for (int m = 0; m < 4; ++m)
#pragma unroll
            for (int n = 0; n < 4; ++n)
                acc[m][n] = __builtin_amdgcn_mfma_f32_16x16x32_bf16(af[m], bfr[n], acc[m][n], 0, 0, 0);
    }

    // epilogue: C/D layout col = lane&15, row = (lane>>4)*4 + r
#pragma unroll
    for (int m = 0; m < 4; ++m)
#pragma unroll
        for (int n = 0; n < 4; ++n)
#pragma unroll
            for (int r = 0; r < 4; ++r) {
                int row = bm + wr + m * 16 + lg * 4 + r;
                int col = bn + wc + n * 16 + lr;
                if (OUTB)
                    ((u16*)Cp)[(size_t)row * ldc + col] = f2bf(acc[m][n][r]);
                else
                    ((float*)Cp)[(size_t)row * ldc + col] = acc[m][n][r];
            }
}

// ---------------------------------------------------------------------------
// MFMA attention, one block per (local chunk ln, head h), 512 threads (8 waves),
// wave w owns q-rows w*16..w*16+15 of the chunk.
//   bd = q @ relk^T -> G in LDS (bf16); ac = q @ k_ctx^T (regs);
//   logits = 50*tanh((ac + shift(G))/50); softmax in regs; P -> LDS bf16;
//   out = P @ V (V staged transposed in LDS).
// rel_shift: bd[c,x] = G[c][x-c] (x>=c) else G[c-1][x-c+256]; G[.][255]=0
// (relk row 255 is zero-padded so MFMA produces the zero pad column).
// qkv rows are segment rows: q row = (ln+1)*128 + c ; ctx pos pp -> ln*128+1+pp.
// ---------------------------------------------------------------------------
__global__ __launch_bounds__(512)
void attn_mfma(const u16* __restrict__ qkv, const u16* __restrict__ relk,
               u16* __restrict__ attn_out)
{
    __shared__ __align__(16) u16 kv_s[256 * 128];   // relk -> k_ctx -> V^T
    __shared__ __align__(16) u16 g_s[128 * 264];    // G -> P

    const int ln = blockIdx.x, h = blockIdx.y;
    const int tid = threadIdx.x;
    const int w = tid >> 6, l = tid & 63;
    const int lr = l & 15, lg = l >> 4;
    const size_t qrow0 = (size_t)(ln + 1) * 128;

    // ---- Q fragments (registers, no LDS)
    bf16x8 qa[4];
    {
        const u16* qp = qkv + (qrow0 + w * 16 + lr) * QKVW_ + h * HD_ + lg * 8;
#pragma unroll
        for (int kk = 0; kk < 4; ++kk) qa[kk] = *(const bf16x8*)(qp + kk * 32);
    }

    // ---- stage relk [256 rows][128] bf16 (swizzled 16B slots)
#pragma unroll
    for (int it = 0; it < 8; ++it) {
        int sid = it * 512 + tid;          // 0..4095
        int row = sid >> 4, sl = sid & 15;
        int4 v = *(const int4*)(relk + (size_t)row * H_ + h * HD_ + sl * 8);
        *(int4*)&kv_s[row * 128 + (((sl ^ (row & 15)) << 3))] = v;
    }
    __syncthreads();

    // ---- bd MFMA: sacc[n] over 16 col-tiles
    f32x4 sacc[16];
#pragma unroll
    for (int n = 0; n < 16; ++n) sacc[n] = (f32x4){0.f, 0.f, 0.f, 0.f};
#pragma unroll
    for (int n = 0; n < 16; ++n)
#pragma unroll
        for (int kk = 0; kk < 4; ++kk) {
            int row = n * 16 + lr;
            int sl = kk * 4 + lg;
            bf16x8 bfrag = *(const bf16x8*)&kv_s[row * 128 + ((sl ^ (row & 15)) << 3)];
            sacc[n] = __builtin_amdgcn_mfma_f32_16x16x32_bf16(qa[kk], bfrag, sacc[n], 0, 0, 0);
        }

    // ---- write G (bf16) rows c..c+3 of this lane
    const int c = w * 16 + lg * 4;
#pragma unroll
    for (int n = 0; n < 16; ++n)
#pragma unroll
        for (int r = 0; r < 4; ++r)
            g_s[(c + r) * 264 + n * 16 + lr] = f2bf(sacc[n][r]);
    __syncthreads();

    // ---- stage k_ctx (ctx pos pp -> seg row ln*128+1+pp); pp=255 -> 0
#pragma unroll
    for (int it = 0; it < 8; ++it) {
        int sid = it * 512 + tid;
        int row = sid >> 4, sl = sid & 15;
        int4 v = make_int4(0, 0, 0, 0);
        if (row < 255)
            v = *(const int4*)(qkv + (size_t)(ln * 128 + 1 + row) * QKVW_ + H_ + h * HD_ + sl * 8);
        *(int4*)&kv_s[row * 128 + ((sl ^ (row & 15)) << 3)] = v;
    }
    __syncthreads();

    // ---- ac MFMA (reuse sacc)
#pragma unroll
    for (int n = 0; n < 16; ++n) sacc[n] = (f32x4){0.f, 0.f, 0.f, 0.f};
#pragma unroll
    for (int n = 0; n < 16; ++n)
#pragma unroll
        for (int kk = 0; kk < 4; ++kk) {
            int row = n * 16 + lr;
            int sl = kk * 4 + lg;
            bf16x8 bfrag = *(const bf16x8*)&kv_s[row * 128 + ((sl ^ (row & 15)) << 3)];
            sacc[n] = __builtin_amdgcn_mfma_f32_16x16x32_bf16(qa[kk], bfrag, sacc[n], 0, 0, 0);
        }

    // ---- combine with shifted G, softcap
#pragma unroll
    for (int n = 0; n < 16; ++n)
#pragma unroll
        for (int r = 0; r < 4; ++r) {
            int cc = c + r;
            int x = n * 16 + lr;
            float val;
            if (x == 255) {
                val = -1e30f;
            } else {
                int dx = x - cc;
                u16 bdu = (dx >= 0) ? g_s[cc * 264 + dx]
                                    : g_s[(cc - 1) * 264 + dx + 256];
                float t = (sacc[n][r] + bf2f(bdu)) * (1.f / 50.f);
                val = 50.f * tanhf(t);
            }
            sacc[n][r] = val;
        }

    // ---- softmax per row (distributed over 16 lanes sharing lg)
#pragma unroll
    for (int r = 0; r < 4; ++r) {
        float m = -1e30f;
#pragma unroll
        for (int n = 0; n < 16; ++n) m = fmaxf(m, sacc[n][r]);
#pragma unroll
        for (int off = 1; off < 16; off <<= 1) m = fmaxf(m, __shfl_xor(m, off, 16));
        float s = 0.f;
#pragma unroll
        for (int n = 0; n < 16; ++n) {
            float e = __expf(sacc[n][r] - m);
            sacc[n][r] = e;
            s += e;
        }
#pragma unroll
        for (int off = 1; off < 16; off <<= 1) s += __shfl_xor(s, off, 16);
        float inv = 1.f / s;
#pragma unroll
        for (int n = 0; n < 16; ++n) sacc[n][r] *= inv;
    }
    __syncthreads();   // all G reads + k_ctx reads complete

    // ---- write P (overwrite G region)
#pragma unroll
    for (int n = 0; n < 16; ++n)
#pragma unroll
        for (int r = 0; r < 4; ++r)
            g_s[(c + r) * 264 + n * 16 + lr] = f2bf(sacc[n][r]);

    // ---- stage V^T: vt[d][x] (row stride 256, swizzled 16B slots); x=255 -> 0
#pragma unroll
    for (int it = 0; it < 8; ++it) {
        int ti = it * 512 + tid;           // x = ti>>4, dgroup = ti&15
        int x = ti >> 4, dg = ti & 15;
        int4 vv = make_int4(0, 0, 0, 0);
        if (x < 255)
            vv = *(const int4*)(qkv + (size_t)(ln * 128 + 1 + x) * QKVW_ + 2 * H_ + h * HD_ + dg * 8);
        const u16* vs = (const u16*)&vv;
#pragma unroll
        for (int i = 0; i < 8; ++i) {
            int d = dg * 8 + i;
            int sl = x >> 3, xo = x & 7;
            kv_s[d * 256 + (((sl ^ (d & 15)) << 3) + xo)] = vs[i];
        }
    }
    __syncthreads();

    // ---- PV MFMA: out[c][d], K = 256 over x
    f32x4 oacc[8];
#pragma unroll
    for (int n = 0; n < 8; ++n) oacc[n] = (f32x4){0.f, 0.f, 0.f, 0.f};
#pragma unroll
    for (int kk = 0; kk < 8; ++kk) {
        int prow = w * 16 + lr;
        bf16x8 pa = *(const bf16x8*)&g_s[prow * 264 + kk * 32 + lg * 8];
#pragma unroll
        for (int n = 0; n < 8; ++n) {
            int d = n * 16 + lr;
            int sl = kk * 4 + lg;
            bf16x8 vb = *(const bf16x8*)&kv_s[d * 256 + ((sl ^ (d & 15)) << 3)];
            oacc[n] = __builtin_amdgcn_mfma_f32_16x16x32_bf16(pa, vb, oacc[n], 0, 0, 0);
        }
    }

    // ---- write attn output (bf16)
#pragma unroll
    for (int n = 0; n < 8; ++n)
#pragma unroll
        for (int r = 0; r < 4; ++r)
            attn_out[(size_t)(ln * 128 + c + r) * H_ + h * HD_ + n * 16 + lr] = f2bf(oacc[n][r]);
}

// ---------------------------------------------------------------------------
extern "C" void kernel_launch(void* const* d_in, const int* in_sizes, int n_in,
                              void* d_out, int out_size, void* d_ws, size_t ws_size,
                              hipStream_t stream)
{
    (void)in_sizes; (void)n_in; (void)out_size;

    const float* hs    = (const float*)d_in[0];
    const float* pos   = (const float*)d_in[1];
    const float* Wq    = (const float*)d_in[2];
    const float* Wk    = (const float*)d_in[3];
    const float* Wv    = (const float*)d_in[4];
    const float* Wrel  = (const float*)d_in[5];
    const float* Wpost = (const float*)d_in[6];
    const float* pds   = (const float*)d_in[7];
    float* out = (float*)d_out;

    const long long WW = (long long)H_ * H_;        // 2359296
    const long long POSN = 256LL * H_;              // 393216

    // fixed workspace (u16 elems): wqkv | wpost | wrel | posb | relkb
    const long long fixed_elems = (long long)QKVW_ * H_ + 2 * WW + 2 * POSN;

    // choose largest segment size G (chunks) that fits
    int G = 0;
    const int cand[6] = {32, 16, 8, 4, 2, 1};
    for (int ci = 0; ci < 6; ++ci) {
        int g = cand[ci];
        long long seg_elems = (long long)(g + 1) * 128 * (H_ + QKVW_)  // hsb + qkvb
                            + (long long)g * 128 * H_;                 // attb
        if ((fixed_elems + seg_elems) * 2 <= (long long)ws_size) { G = g; break; }
    }
    if (G == 0) return;

    u16* wqkvb = (u16*)d_ws;
    u16* wpostb = wqkvb + (long long)QKVW_ * H_;
    u16* wrelb  = wpostb + WW;
    u16* posb   = wrelb + WW;
    u16* relkb  = posb + POSN;
    u16* hsb    = relkb + POSN;
    u16* qkvb   = hsb + (long long)(G + 1) * 128 * H_;
    u16* attb   = qkvb + (long long)(G + 1) * 128 * QKVW_;

    dim3 blk(256);
    const long long BIG = 1LL << 60;

    // ---- weight / pos conversions (scales baked in)
    conv_bf16<<<dim3(WW / 1024), blk, 0, stream>>>(Wq, 0, wqkvb,            WW, 0, BIG, 1, pds, H_);
    conv_bf16<<<dim3(WW / 1024), blk, 0, stream>>>(Wk, 0, wqkvb + WW,       WW, 0, BIG, 2, nullptr, H_);
    conv_bf16<<<dim3(WW / 1024), blk, 0, stream>>>(Wv, 0, wqkvb + 2 * WW,   WW, 0, BIG, 0, nullptr, H_);
    conv_bf16<<<dim3(WW / 1024), blk, 0, stream>>>(Wpost, 0, wpostb,        WW, 0, BIG, 0, nullptr, H_);
    conv_bf16<<<dim3(WW / 1024), blk, 0, stream>>>(Wrel, 0, wrelb,          WW, 0, BIG, 0, nullptr, H_);
    conv_bf16<<<dim3(POSN / 1024), blk, 0, stream>>>(pos, 0, posb, POSN, 0, 255LL * H_, 0, nullptr, H_);

    // ---- relk = posb @ wrel^T  [256][1536] bf16 (row 255 = 0 automatically)
    gemm_bt<1><<<dim3(H_ / 128, 2), blk, 0, stream>>>(posb, wrelb, relkb, 256, H_, H_, H_);

    for (int b = 0; b < B_; ++b) {
        for (int n0 = 0; n0 < NB_; n0 += G) {
            const int Mh = (G + 1) * 128;          // rows incl. front-halo chunk
            const long long hs_base = ((long long)b * S_ + (long long)(n0 - 1) * CHUNK_) * H_;
            const long long zb = (n0 == 0) ? (long long)CHUNK_ * H_ : 0;
            const long long hn = (long long)Mh * H_;

            conv_bf16<<<dim3(hn / 1024), blk, 0, stream>>>(hs, hs_base, hsb, hn, zb, BIG, 0, nullptr, H_);

            gemm_bt<1><<<dim3(QKVW_ / 128, Mh / 128), blk, 0, stream>>>(
                hsb, wqkvb, qkvb, Mh, QKVW_, H_, QKVW_);

            attn_mfma<<<dim3(G, NH_), dim3(512), 0, stream>>>(qkvb, relkb, attb);

            gemm_bt<0><<<dim3(H_ / 128, G), blk, 0, stream>>>(
                attb, wpostb, out + ((long long)b * S_ + (long long)n0 * CHUNK_) * H_,
                G * CHUNK_, H_, H_, H_);
        }
    }
}

// Round 5
// 738.474 us; speedup vs baseline: 10.0655x; 2.4778x over previous
//
#include <hip/hip_runtime.h>
#include <hip/hip_bf16.h>
#include <math.h>

// ---------------------------------------------------------------------------
// Gemma audio layer, round 4: round-3 plan with the LDS-pointer-array compile
// fix (no addrspace(3) pointers stored in arrays; integer offsets instead).
//   - epilogue: C tile staged via LDS -> coalesced 16B/lane row stores
//   - staging: global_load_lds width=16, linear double-buffered LDS
//   - attention kernel unchanged from round 2
// ---------------------------------------------------------------------------

#define NH_    12
#define HD_    128
#define H_     1536
#define B_     4
#define S_     4096
#define CHUNK_ 128
#define CTX_   255
#define NB_    32
#define QKVW_  4608

typedef unsigned short u16;
typedef short bf16x8 __attribute__((ext_vector_type(8)));
typedef float f32x4 __attribute__((ext_vector_type(4)));

static constexpr float Q_SCALE_F = (float)(0.08838834764831845 / 0.6931471805599453);
static constexpr float K_SCALE_F = (float)(1.3132616875182228 / 0.6931471805599453);

__device__ __forceinline__ u16 f2bf(float f) {
    __hip_bfloat16 h = __float2bfloat16(f);
    return __builtin_bit_cast(u16, h);
}
__device__ __forceinline__ float bf2f(u16 u) {
    unsigned int t = ((unsigned int)u) << 16;
    return __builtin_bit_cast(float, t);
}

__device__ __forceinline__ void gload_lds16(const u16* src_global, u16* dst_lds) {
    __builtin_amdgcn_global_load_lds(
        (const __attribute__((address_space(1))) unsigned int*)src_global,
        (__attribute__((address_space(3))) unsigned int*)dst_lds,
        16, 0, 0);
}

// ---------------------------------------------------------------------------
// fp32 -> bf16 conversion with optional scaling / zero-fill.
// dst[i] = (i<zero_below || i>=zero_from) ? 0 : scale * src[base+i]
// mode: 0 none, 1 per-row q-scale (QS*softplus(pds[(i/ncols)&127])), 2 K_SCALE
// ---------------------------------------------------------------------------
__global__ __launch_bounds__(256)
void conv_bf16(const float* __restrict__ src, long long base,
               u16* __restrict__ dst, long long n,
               long long zero_below, long long zero_from,
               int mode, const float* __restrict__ pds, int ncols)
{
    long long i = ((long long)blockIdx.x * 256 + threadIdx.x) * 4;
    if (i >= n) return;
    float4 v = make_float4(0.f, 0.f, 0.f, 0.f);
    if (i >= zero_below && i < zero_from)
        v = *(const float4*)(src + base + i);
    float s = 1.f;
    if (mode == 1) {
        int row = (int)(i / ncols);
        float x = pds[row & 127];
        float sp = (x > 20.f) ? x : log1pf(__expf(x));
        s = Q_SCALE_F * sp;
    } else if (mode == 2) {
        s = K_SCALE_F;
    }
    ushort4 o = make_ushort4(f2bf(v.x * s), f2bf(v.y * s), f2bf(v.z * s), f2bf(v.w * s));
    *(ushort4*)(dst + i) = o;
}

// ---------------------------------------------------------------------------
// bf16 GEMM  C[M,N] = A[M,K] @ B[N,K]^T  (row-major bf16, K mult of 32,
// M,N mult of 128). OUTB: 1 -> bf16 C (LDS-staged coalesced stores),
// 0 -> fp32 C (direct 64B-segment stores).
// 128x128 tile, 4 waves, 16x16x32 MFMA, global_load_lds double-buffer.
// LDS buffers addressed by integer offsets (no addrspace pointer arrays).
// ---------------------------------------------------------------------------
template<int OUTB>
__global__ __launch_bounds__(256)
void gemm_bt(const u16* __restrict__ A, const u16* __restrict__ B,
             void* __restrict__ Cp, int M, int N, int K, int ldc)
{
    // 32 KB: A0 | A1 | B0 | B1 (8 KB each); epilogue aliases cbuf (17 KB)
    __shared__ __align__(16) u16 lds[4 * 4096];

    const int tid = threadIdx.x;
    const int w = tid >> 6, l = tid & 63;
    const int lr = l & 15, lg = l >> 4;
    const int bm = blockIdx.y * 128, bn = blockIdx.x * 128;
    const int wr = (w >> 1) * 64, wc = (w & 1) * 64;

    // staging geometry: chunk c in {0,1}: 16B slot p = (w*2+c)*64 + l
    // linear LDS tile [row][4 slots of 16B]: row = p>>2, k-slot = p&3
    const u16* srcA[2];
    const u16* srcB[2];
    int pbase[2];
#pragma unroll
    for (int c = 0; c < 2; ++c) {
        const int p = (w * 2 + c) * 64 + l;
        const int row = p >> 2, s = p & 3;
        pbase[c] = p * 8;                     // u16 offset within tile
        srcA[c] = A + (size_t)(bm + row) * K + s * 8;
        srcB[c] = B + (size_t)(bn + row) * K + s * 8;
    }

    f32x4 acc[4][4];
#pragma unroll
    for (int m = 0; m < 4; ++m)
#pragma unroll
        for (int n = 0; n < 4; ++n) acc[m][n] = (f32x4){0.f, 0.f, 0.f, 0.f};

    // prologue: stage tile 0 into buffer 0 (A at 0, B at 2*4096)
#pragma unroll
    for (int c = 0; c < 2; ++c) {
        gload_lds16(srcA[c], lds + pbase[c]);
        gload_lds16(srcB[c], lds + 2 * 4096 + pbase[c]);
    }
    __syncthreads();   // drains vmcnt before barrier

    const int nk = K >> 5;
    int cur = 0;
    for (int t = 0; t < nk; ++t) {
        const int co = cur * 4096;            // current buffer offset
        if (t + 1 < nk) {
            const int k1 = (t + 1) << 5;
            const int no = (cur ^ 1) * 4096;  // next buffer offset
#pragma unroll
            for (int c = 0; c < 2; ++c) {
                gload_lds16(srcA[c] + k1, lds + no + pbase[c]);
                gload_lds16(srcB[c] + k1, lds + 2 * 4096 + no + pbase[c]);
            }
        }
        bf16x8 af[4], bfr[4];
#pragma unroll
        for (int m = 0; m < 4; ++m)
            af[m] = *(const bf16x8*)&lds[co + (wr + m * 16 + lr) * 32 + lg * 8];
#pragma unroll
        for (int n = 0; n < 4; ++n)
            bfr[n] = *(const bf16x8*)&lds[2 * 4096 + co + (wc + n * 16 + lr) * 32 + lg * 8];
#pragma unroll
        for (int m = 0; m < 4; ++m)
#pragma unroll
            for (int n = 0; n < 4; ++n)
                acc[m][n] = __builtin_amdgcn_mfma_f32_16x16x32_bf16(af[m], bfr[n], acc[m][n], 0, 0, 0);
        __syncthreads();   // drains stage vmcnt + guards buffer overwrite
        cur ^= 1;
    }

    // C/D layout: col = lane&15 (lr), row = lg*4 + r
    if (OUTB) {
        // coalesced epilogue via LDS: halves of 64 rows, stride 136 u16
#pragma unroll
        for (int h = 0; h < 2; ++h) {
            if (wr == h * 64) {
#pragma unroll
                for (int m = 0; m < 4; ++m)
#pragma unroll
                    for (int n = 0; n < 4; ++n)
#pragma unroll
                        for (int r = 0; r < 4; ++r)
                            lds[(m * 16 + lg * 4 + r) * 136 + wc + n * 16 + lr] =
                                f2bf(acc[m][n][r]);
            }
            __syncthreads();
#pragma unroll
            for (int it = 0; it < 4; ++it) {
                const int sid = it * 256 + tid;
                const int row = sid >> 4, sl = sid & 15;
                int4 val = *(const int4*)&lds[row * 136 + sl * 8];
                *(int4*)((u16*)Cp + (size_t)(bm + h * 64 + row) * ldc + bn + sl * 8) = val;
            }
            __syncthreads();
        }
    } else {
        // fp32 out: 16 lanes x 4B = 64B contiguous segments (acceptable)
#pragma unroll
        for (int m = 0; m < 4; ++m)
#pragma unroll
            for (int n = 0; n < 4; ++n)
#pragma unroll
                for (int r = 0; r < 4; ++r) {
                    const int row = bm + wr + m * 16 + lg * 4 + r;
                    const int col = bn + wc + n * 16 + lr;
                    ((float*)Cp)[(size_t)row * ldc + col] = acc[m][n][r];
                }
    }
}

// ---------------------------------------------------------------------------
// MFMA attention (unchanged from round 2): one block per (local chunk, head),
// 8 waves. bd = q@relk^T -> G (LDS bf16); ac = q@k_ctx^T; rel-shift combine;
// softcap; in-register softmax; P -> LDS; out = P @ V (V^T in LDS).
// rel_shift: bd[c,x] = G[c][x-c] (x>=c) else G[c-1][x-c+256]; G[.][255]=0.
// ---------------------------------------------------------------------------
__global__ __launch_bounds__(512)
void attn_mfma(const u16* __restrict__ qkv, const u16* __restrict__ relk,
               u16* __restrict__ attn_out)
{
    __shared__ __align__(16) u16 kv_s[256 * 128];   // relk -> k_ctx -> V^T
    __shared__ __align__(16) u16 g_s[128 * 264];    // G -> P

    const int ln = blockIdx.x, h = blockIdx.y;
    const int tid = threadIdx.x;
    const int w = tid >> 6, l = tid & 63;
    const int lr = l & 15, lg = l >> 4;
    const size_t qrow0 = (size_t)(ln + 1) * 128;

    bf16x8 qa[4];
    {
        const u16* qp = qkv + (qrow0 + w * 16 + lr) * QKVW_ + h * HD_ + lg * 8;
#pragma unroll
        for (int kk = 0; kk < 4; ++kk) qa[kk] = *(const bf16x8*)(qp + kk * 32);
    }

#pragma unroll
    for (int it = 0; it < 8; ++it) {
        int sid = it * 512 + tid;
        int row = sid >> 4, sl = sid & 15;
        int4 v = *(const int4*)(relk + (size_t)row * H_ + h * HD_ + sl * 8);
        *(int4*)&kv_s[row * 128 + (((sl ^ (row & 15)) << 3))] = v;
    }
    __syncthreads();

    f32x4 sacc[16];
#pragma unroll
    for (int n = 0; n < 16; ++n) sacc[n] = (f32x4){0.f, 0.f, 0.f, 0.f};
#pragma unroll
    for (int n = 0; n < 16; ++n)
#pragma unroll
        for (int kk = 0; kk < 4; ++kk) {
            int row = n * 16 + lr;
            int sl = kk * 4 + lg;
            bf16x8 bfrag = *(const bf16x8*)&kv_s[row * 128 + ((sl ^ (row & 15)) << 3)];
            sacc[n] = __builtin_amdgcn_mfma_f32_16x16x32_bf16(qa[kk], bfrag, sacc[n], 0, 0, 0);
        }

    const int c = w * 16 + lg * 4;
#pragma unroll
    for (int n = 0; n < 16; ++n)
#pragma unroll
        for (int r = 0; r < 4; ++r)
            g_s[(c + r) * 264 + n * 16 + lr] = f2bf(sacc[n][r]);
    __syncthreads();

#pragma unroll
    for (int it = 0; it < 8; ++it) {
        int sid = it * 512 + tid;
        int row = sid >> 4, sl = sid & 15;
        int4 v = make_int4(0, 0, 0, 0);
        if (row < 255)
            v = *(const int4*)(qkv + (size_t)(ln * 128 + 1 + row) * QKVW_ + H_ + h * HD_ + sl * 8);
        *(int4*)&kv_s[row * 128 + ((sl ^ (row & 15)) << 3)] = v;
    }
    __syncthreads();

#pragma unroll
    for (int n = 0; n < 16; ++n) sacc[n] = (f32x4){0.f, 0.f, 0.f, 0.f};
#pragma unroll
    for (int n = 0; n < 16; ++n)
#pragma unroll
        for (int kk = 0; kk < 4; ++kk) {
            int row = n * 16 + lr;
            int sl = kk * 4 + lg;
            bf16x8 bfrag = *(const bf16x8*)&kv_s[row * 128 + ((sl ^ (row & 15)) << 3)];
            sacc[n] = __builtin_amdgcn_mfma_f32_16x16x32_bf16(qa[kk], bfrag, sacc[n], 0, 0, 0);
        }

#pragma unroll
    for (int n = 0; n < 16; ++n)
#pragma unroll
        for (int r = 0; r < 4; ++r) {
            int cc = c + r;
            int x = n * 16 + lr;
            float val;
            if (x == 255) {
                val = -1e30f;
            } else {
                int dx = x - cc;
                u16 bdu = (dx >= 0) ? g_s[cc * 264 + dx]
                                    : g_s[(cc - 1) * 264 + dx + 256];
                float t = (sacc[n][r] + bf2f(bdu)) * (1.f / 50.f);
                val = 50.f * tanhf(t);
            }
            sacc[n][r] = val;
        }

#pragma unroll
    for (int r = 0; r < 4; ++r) {
        float m = -1e30f;
#pragma unroll
        for (int n = 0; n < 16; ++n) m = fmaxf(m, sacc[n][r]);
#pragma unroll
        for (int off = 1; off < 16; off <<= 1) m = fmaxf(m, __shfl_xor(m, off, 16));
        float s = 0.f;
#pragma unroll
        for (int n = 0; n < 16; ++n) {
            float e = __expf(sacc[n][r] - m);
            sacc[n][r] = e;
            s += e;
        }
#pragma unroll
        for (int off = 1; off < 16; off <<= 1) s += __shfl_xor(s, off, 16);
        float inv = 1.f / s;
#pragma unroll
        for (int n = 0; n < 16; ++n) sacc[n][r] *= inv;
    }
    __syncthreads();

#pragma unroll
    for (int n = 0; n < 16; ++n)
#pragma unroll
        for (int r = 0; r < 4; ++r)
            g_s[(c + r) * 264 + n * 16 + lr] = f2bf(sacc[n][r]);

#pragma unroll
    for (int it = 0; it < 8; ++it) {
        int ti = it * 512 + tid;
        int x = ti >> 4, dg = ti & 15;
        int4 vv = make_int4(0, 0, 0, 0);
        if (x < 255)
            vv = *(const int4*)(qkv + (size_t)(ln * 128 + 1 + x) * QKVW_ + 2 * H_ + h * HD_ + dg * 8);
        const u16* vs = (const u16*)&vv;
#pragma unroll
        for (int i = 0; i < 8; ++i) {
            int d = dg * 8 + i;
            int sl = x >> 3, xo = x & 7;
            kv_s[d * 256 + (((sl ^ (d & 15)) << 3) + xo)] = vs[i];
        }
    }
    __syncthreads();

    f32x4 oacc[8];
#pragma unroll
    for (int n = 0; n < 8; ++n) oacc[n] = (f32x4){0.f, 0.f, 0.f, 0.f};
#pragma unroll
    for (int kk = 0; kk < 8; ++kk) {
        int prow = w * 16 + lr;
        bf16x8 pa = *(const bf16x8*)&g_s[prow * 264 + kk * 32 + lg * 8];
#pragma unroll
        for (int n = 0; n < 8; ++n) {
            int d = n * 16 + lr;
            int sl = kk * 4 + lg;
            bf16x8 vb = *(const bf16x8*)&kv_s[d * 256 + ((sl ^ (d & 15)) << 3)];
            oacc[n] = __builtin_amdgcn_mfma_f32_16x16x32_bf16(pa, vb, oacc[n], 0, 0, 0);
        }
    }

#pragma unroll
    for (int n = 0; n < 8; ++n)
#pragma unroll
        for (int r = 0; r < 4; ++r)
            attn_out[(size_t)(ln * 128 + c + r) * H_ + h * HD_ + n * 16 + lr] = f2bf(oacc[n][r]);
}

// ---------------------------------------------------------------------------
extern "C" void kernel_launch(void* const* d_in, const int* in_sizes, int n_in,
                              void* d_out, int out_size, void* d_ws, size_t ws_size,
                              hipStream_t stream)
{
    (void)in_sizes; (void)n_in; (void)out_size;

    const float* hs    = (const float*)d_in[0];
    const float* pos   = (const float*)d_in[1];
    const float* Wq    = (const float*)d_in[2];
    const float* Wk    = (const float*)d_in[3];
    const float* Wv    = (const float*)d_in[4];
    const float* Wrel  = (const float*)d_in[5];
    const float* Wpost = (const float*)d_in[6];
    const float* pds   = (const float*)d_in[7];
    float* out = (float*)d_out;

    const long long WW = (long long)H_ * H_;
    const long long POSN = 256LL * H_;
    const long long fixed_elems = (long long)QKVW_ * H_ + 2 * WW + 2 * POSN;

    int G = 0;
    const int cand[6] = {32, 16, 8, 4, 2, 1};
    for (int ci = 0; ci < 6; ++ci) {
        int g = cand[ci];
        long long seg_elems = (long long)(g + 1) * 128 * (H_ + QKVW_)
                            + (long long)g * 128 * H_;
        if ((fixed_elems + seg_elems) * 2 <= (long long)ws_size) { G = g; break; }
    }
    if (G == 0) return;

    u16* wqkvb  = (u16*)d_ws;
    u16* wpostb = wqkvb + (long long)QKVW_ * H_;
    u16* wrelb  = wpostb + WW;
    u16* posb   = wrelb + WW;
    u16* relkb  = posb + POSN;
    u16* hsb    = relkb + POSN;
    u16* qkvb   = hsb + (long long)(G + 1) * 128 * H_;
    u16* attb   = qkvb + (long long)(G + 1) * 128 * QKVW_;

    dim3 blk(256);
    const long long BIG = 1LL << 60;

    conv_bf16<<<dim3(WW / 1024), blk, 0, stream>>>(Wq, 0, wqkvb,          WW, 0, BIG, 1, pds, H_);
    conv_bf16<<<dim3(WW / 1024), blk, 0, stream>>>(Wk, 0, wqkvb + WW,     WW, 0, BIG, 2, nullptr, H_);
    conv_bf16<<<dim3(WW / 1024), blk, 0, stream>>>(Wv, 0, wqkvb + 2 * WW, WW, 0, BIG, 0, nullptr, H_);
    conv_bf16<<<dim3(WW / 1024), blk, 0, stream>>>(Wpost, 0, wpostb,      WW, 0, BIG, 0, nullptr, H_);
    conv_bf16<<<dim3(WW / 1024), blk, 0, stream>>>(Wrel, 0, wrelb,        WW, 0, BIG, 0, nullptr, H_);
    conv_bf16<<<dim3(POSN / 1024), blk, 0, stream>>>(pos, 0, posb, POSN, 0, 255LL * H_, 0, nullptr, H_);

    gemm_bt<1><<<dim3(H_ / 128, 2), blk, 0, stream>>>(posb, wrelb, relkb, 256, H_, H_, H_);

    for (int b = 0; b < B_; ++b) {
        for (int n0 = 0; n0 < NB_; n0 += G) {
            const int Mh = (G + 1) * 128;
            const long long hs_base = ((long long)b * S_ + (long long)(n0 - 1) * CHUNK_) * H_;
            const long long zb = (n0 == 0) ? (long long)CHUNK_ * H_ : 0;
            const long long hn = (long long)Mh * H_;

            conv_bf16<<<dim3(hn / 1024), blk, 0, stream>>>(hs, hs_base, hsb, hn, zb, BIG, 0, nullptr, H_);

            gemm_bt<1><<<dim3(QKVW_ / 128, Mh / 128), blk, 0, stream>>>(
                hsb, wqkvb, qkvb, Mh, QKVW_, H_, QKVW_);

            attn_mfma<<<dim3(G, NH_), dim3(512), 0, stream>>>(qkvb, relkb, attb);

            gemm_bt<0><<<dim3(H_ / 128, G), blk, 0, stream>>>(
                attb, wpostb, out + ((long long)b * S_ + (long long)n0 * CHUNK_) * H_,
                G * CHUNK_, H_, H_, H_);
        }
    }
}

// Round 6
// 729.724 us; speedup vs baseline: 10.1862x; 1.0120x over previous
//
#include <hip/hip_runtime.h>
#include <hip/hip_bf16.h>
#include <math.h>

// ---------------------------------------------------------------------------
// Gemma audio layer, round 5: GEMM K-loop -> 4-buffer ring pipeline with
// counted vmcnt (T4) + raw s_barrier (no vmcnt(0) drain), setprio around MFMA
// (T5), bijective XCD-aware block swizzle (T1). Tile unchanged 128x128xBK32.
// Epilogue + attention + conv identical to round 4 (passed, absmax 4.1e-3).
// ---------------------------------------------------------------------------

#define NH_    12
#define HD_    128
#define H_     1536
#define B_     4
#define S_     4096
#define CHUNK_ 128
#define CTX_   255
#define NB_    32
#define QKVW_  4608

typedef unsigned short u16;
typedef short bf16x8 __attribute__((ext_vector_type(8)));
typedef float f32x4 __attribute__((ext_vector_type(4)));

static constexpr float Q_SCALE_F = (float)(0.08838834764831845 / 0.6931471805599453);
static constexpr float K_SCALE_F = (float)(1.3132616875182228 / 0.6931471805599453);

__device__ __forceinline__ u16 f2bf(float f) {
    __hip_bfloat16 h = __float2bfloat16(f);
    return __builtin_bit_cast(u16, h);
}
__device__ __forceinline__ float bf2f(u16 u) {
    unsigned int t = ((unsigned int)u) << 16;
    return __builtin_bit_cast(float, t);
}

__device__ __forceinline__ void gload_lds16(const u16* src_global, u16* dst_lds) {
    __builtin_amdgcn_global_load_lds(
        (const __attribute__((address_space(1))) unsigned int*)src_global,
        (__attribute__((address_space(3))) unsigned int*)dst_lds,
        16, 0, 0);
}

// ---------------------------------------------------------------------------
// fp32 -> bf16 conversion with optional scaling / zero-fill.
// ---------------------------------------------------------------------------
__global__ __launch_bounds__(256)
void conv_bf16(const float* __restrict__ src, long long base,
               u16* __restrict__ dst, long long n,
               long long zero_below, long long zero_from,
               int mode, const float* __restrict__ pds, int ncols)
{
    long long i = ((long long)blockIdx.x * 256 + threadIdx.x) * 4;
    if (i >= n) return;
    float4 v = make_float4(0.f, 0.f, 0.f, 0.f);
    if (i >= zero_below && i < zero_from)
        v = *(const float4*)(src + base + i);
    float s = 1.f;
    if (mode == 1) {
        int row = (int)(i / ncols);
        float x = pds[row & 127];
        float sp = (x > 20.f) ? x : log1pf(__expf(x));
        s = Q_SCALE_F * sp;
    } else if (mode == 2) {
        s = K_SCALE_F;
    }
    ushort4 o = make_ushort4(f2bf(v.x * s), f2bf(v.y * s), f2bf(v.z * s), f2bf(v.w * s));
    *(ushort4*)(dst + i) = o;
}

// ---------------------------------------------------------------------------
// bf16 GEMM  C[M,N] = A[M,K] @ B[N,K]^T  (row-major bf16, K mult of 128,
// M,N mult of 128). OUTB: 1 -> bf16 C (LDS-staged coalesced stores),
// 0 -> fp32 C.
// 128x128 tile, 4 waves, 16x16x32 MFMA.
// K-loop: ring of 4 LDS buffers (A at buf*4096, B at 16384+buf*4096 u16),
// stage 2 tiles ahead via global_load_lds, ONE raw s_barrier per iter,
// counted s_waitcnt vmcnt(8) (2 tiles in flight) -- no vmcnt(0) drain.
// Ring-safety: buf written by stage(t+2) was last read at compute(t-2),
// finished by all waves before barrier(t-1), which precedes the stage issue.
// ---------------------------------------------------------------------------
#define STAGE(kt, bufc) do {                                                   \
    const int _ko = (kt) << 5;                                                 \
    gload_lds16(srcA[0] + _ko, lds + (bufc) * 4096 + pbase[0]);                \
    gload_lds16(srcA[1] + _ko, lds + (bufc) * 4096 + pbase[1]);                \
    gload_lds16(srcB[0] + _ko, lds + 16384 + (bufc) * 4096 + pbase[0]);        \
    gload_lds16(srcB[1] + _ko, lds + 16384 + (bufc) * 4096 + pbase[1]);        \
} while (0)

#define ITER(t, b) do {                                                        \
    if ((t) + 2 < nk) {                                                        \
        STAGE((t) + 2, ((b) + 2) & 3);                                         \
        asm volatile("s_waitcnt vmcnt(8)" ::: "memory");                       \
    } else if ((t) + 1 < nk) {                                                 \
        asm volatile("s_waitcnt vmcnt(4)" ::: "memory");                       \
    } else {                                                                   \
        asm volatile("s_waitcnt vmcnt(0)" ::: "memory");                       \
    }                                                                          \
    __builtin_amdgcn_s_barrier();                                              \
    asm volatile("" ::: "memory");                                            \
    bf16x8 af[4], bfr[4];                                                      \
    _Pragma("unroll")                                                          \
    for (int m = 0; m < 4; ++m)                                                \
        af[m] = *(const bf16x8*)&lds[(b) * 4096 + (wr + m * 16 + lr) * 32 + lg * 8]; \
    _Pragma("unroll")                                                          \
    for (int n = 0; n < 4; ++n)                                                \
        bfr[n] = *(const bf16x8*)&lds[16384 + (b) * 4096 + (wc + n * 16 + lr) * 32 + lg * 8]; \
    __builtin_amdgcn_s_setprio(1);                                             \
    _Pragma("unroll")                                                          \
    for (int m = 0; m < 4; ++m)                                                \
        _Pragma("unroll")                                                      \
        for (int n = 0; n < 4; ++n)                                            \
            acc[m][n] = __builtin_amdgcn_mfma_f32_16x16x32_bf16(af[m], bfr[n], acc[m][n], 0, 0, 0); \
    __builtin_amdgcn_s_setprio(0);                                             \
} while (0)

template<int OUTB>
__global__ __launch_bounds__(256)
void gemm_bt(const u16* __restrict__ A, const u16* __restrict__ B,
             void* __restrict__ Cp, int M, int N, int K, int ldc)
{
    // 64 KB: A ring 4x8KB at [0..16384) u16, B ring 4x8KB at [16384..32768).
    // Epilogue cbuf aliases lds[0..8704) -- disjoint from last-read buf 3
    // (A3 at [12288..16384), B3 at [28672..32768)) since nk % 4 == 0.
    __shared__ __align__(16) u16 lds[32768];

    const int tid = threadIdx.x;
    const int w = tid >> 6, l = tid & 63;
    const int lr = l & 15, lg = l >> 4;

    // T1: bijective XCD-aware swizzle (m204) of the linearized block index.
    const int gx = gridDim.x;
    const int nwg = gx * gridDim.y;
    const int orig = blockIdx.y * gx + blockIdx.x;
    const int qq = nwg >> 3, rr = nwg & 7;
    const int xcd = orig & 7, idx = orig >> 3;
    const int swz = (xcd < rr ? xcd * (qq + 1) : rr * (qq + 1) + (xcd - rr) * qq) + idx;
    const int bm = (swz / gx) * 128;
    const int bn = (swz % gx) * 128;

    const int wr = (w >> 1) * 64, wc = (w & 1) * 64;

    // staging geometry: chunk c in {0,1}: 16B slot p = (w*2+c)*64 + l
    // linear LDS tile [row][4 slots of 16B]: row = p>>2, k-slot = p&3
    const u16* srcA[2];
    const u16* srcB[2];
    int pbase[2];
#pragma unroll
    for (int c = 0; c < 2; ++c) {
        const int p = (w * 2 + c) * 64 + l;
        const int row = p >> 2, s = p & 3;
        pbase[c] = p * 8;                     // u16 offset within tile
        srcA[c] = A + (size_t)(bm + row) * K + s * 8;
        srcB[c] = B + (size_t)(bn + row) * K + s * 8;
    }

    f32x4 acc[4][4];
#pragma unroll
    for (int m = 0; m < 4; ++m)
#pragma unroll
        for (int n = 0; n < 4; ++n) acc[m][n] = (f32x4){0.f, 0.f, 0.f, 0.f};

    const int nk = K >> 5;                    // K/32; K%128==0 -> nk%4==0
    STAGE(0, 0);
    STAGE(1, 1);
    for (int t0 = 0; t0 < nk; t0 += 4) {
        ITER(t0 + 0, 0);
        ITER(t0 + 1, 1);
        ITER(t0 + 2, 2);
        ITER(t0 + 3, 3);
    }

    // C/D layout: col = lane&15 (lr), row = lg*4 + r
    if (OUTB) {
        // coalesced epilogue via LDS: halves of 64 rows, stride 136 u16
#pragma unroll
        for (int h = 0; h < 2; ++h) {
            if (wr == h * 64) {
#pragma unroll
                for (int m = 0; m < 4; ++m)
#pragma unroll
                    for (int n = 0; n < 4; ++n)
#pragma unroll
                        for (int r = 0; r < 4; ++r)
                            lds[(m * 16 + lg * 4 + r) * 136 + wc + n * 16 + lr] =
                                f2bf(acc[m][n][r]);
            }
            __syncthreads();
#pragma unroll
            for (int it = 0; it < 4; ++it) {
                const int sid = it * 256 + tid;
                const int row = sid >> 4, sl = sid & 15;
                int4 val = *(const int4*)&lds[row * 136 + sl * 8];
                *(int4*)((u16*)Cp + (size_t)(bm + h * 64 + row) * ldc + bn + sl * 8) = val;
            }
            __syncthreads();
        }
    } else {
#pragma unroll
        for (int m = 0; m < 4; ++m)
#pragma unroll
            for (int n = 0; n < 4; ++n)
#pragma unroll
                for (int r = 0; r < 4; ++r) {
                    const int row = bm + wr + m * 16 + lg * 4 + r;
                    const int col = bn + wc + n * 16 + lr;
                    ((float*)Cp)[(size_t)row * ldc + col] = acc[m][n][r];
                }
    }
}

// ---------------------------------------------------------------------------
// MFMA attention (unchanged from round 2/4).
// ---------------------------------------------------------------------------
__global__ __launch_bounds__(512)
void attn_mfma(const u16* __restrict__ qkv, const u16* __restrict__ relk,
               u16* __restrict__ attn_out)
{
    __shared__ __align__(16) u16 kv_s[256 * 128];   // relk -> k_ctx -> V^T
    __shared__ __align__(16) u16 g_s[128 * 264];    // G -> P

    const int ln = blockIdx.x, h = blockIdx.y;
    const int tid = threadIdx.x;
    const int w = tid >> 6, l = tid & 63;
    const int lr = l & 15, lg = l >> 4;
    const size_t qrow0 = (size_t)(ln + 1) * 128;

    bf16x8 qa[4];
    {
        const u16* qp = qkv + (qrow0 + w * 16 + lr) * QKVW_ + h * HD_ + lg * 8;
#pragma unroll
        for (int kk = 0; kk < 4; ++kk) qa[kk] = *(const bf16x8*)(qp + kk * 32);
    }

#pragma unroll
    for (int it = 0; it < 8; ++it) {
        int sid = it * 512 + tid;
        int row = sid >> 4, sl = sid & 15;
        int4 v = *(const int4*)(relk + (size_t)row * H_ + h * HD_ + sl * 8);
        *(int4*)&kv_s[row * 128 + (((sl ^ (row & 15)) << 3))] = v;
    }
    __syncthreads();

    f32x4 sacc[16];
#pragma unroll
    for (int n = 0; n < 16; ++n) sacc[n] = (f32x4){0.f, 0.f, 0.f, 0.f};
#pragma unroll
    for (int n = 0; n < 16; ++n)
#pragma unroll
        for (int kk = 0; kk < 4; ++kk) {
            int row = n * 16 + lr;
            int sl = kk * 4 + lg;
            bf16x8 bfrag = *(const bf16x8*)&kv_s[row * 128 + ((sl ^ (row & 15)) << 3)];
            sacc[n] = __builtin_amdgcn_mfma_f32_16x16x32_bf16(qa[kk], bfrag, sacc[n], 0, 0, 0);
        }

    const int c = w * 16 + lg * 4;
#pragma unroll
    for (int n = 0; n < 16; ++n)
#pragma unroll
        for (int r = 0; r < 4; ++r)
            g_s[(c + r) * 264 + n * 16 + lr] = f2bf(sacc[n][r]);
    __syncthreads();

#pragma unroll
    for (int it = 0; it < 8; ++it) {
        int sid = it * 512 + tid;
        int row = sid >> 4, sl = sid & 15;
        int4 v = make_int4(0, 0, 0, 0);
        if (row < 255)
            v = *(const int4*)(qkv + (size_t)(ln * 128 + 1 + row) * QKVW_ + H_ + h * HD_ + sl * 8);
        *(int4*)&kv_s[row * 128 + ((sl ^ (row & 15)) << 3)] = v;
    }
    __syncthreads();

#pragma unroll
    for (int n = 0; n < 16; ++n) sacc[n] = (f32x4){0.f, 0.f, 0.f, 0.f};
#pragma unroll
    for (int n = 0; n < 16; ++n)
#pragma unroll
        for (int kk = 0; kk < 4; ++kk) {
            int row = n * 16 + lr;
            int sl = kk * 4 + lg;
            bf16x8 bfrag = *(const bf16x8*)&kv_s[row * 128 + ((sl ^ (row & 15)) << 3)];
            sacc[n] = __builtin_amdgcn_mfma_f32_16x16x32_bf16(qa[kk], bfrag, sacc[n], 0, 0, 0);
        }

#pragma unroll
    for (int n = 0; n < 16; ++n)
#pragma unroll
        for (int r = 0; r < 4; ++r) {
            int cc = c + r;
            int x = n * 16 + lr;
            float val;
            if (x == 255) {
                val = -1e30f;
            } else {
                int dx = x - cc;
                u16 bdu = (dx >= 0) ? g_s[cc * 264 + dx]
                                    : g_s[(cc - 1) * 264 + dx + 256];
                float t = (sacc[n][r] + bf2f(bdu)) * (1.f / 50.f);
                val = 50.f * tanhf(t);
            }
            sacc[n][r] = val;
        }

#pragma unroll
    for (int r = 0; r < 4; ++r) {
        float m = -1e30f;
#pragma unroll
        for (int n = 0; n < 16; ++n) m = fmaxf(m, sacc[n][r]);
#pragma unroll
        for (int off = 1; off < 16; off <<= 1) m = fmaxf(m, __shfl_xor(m, off, 16));
        float s = 0.f;
#pragma unroll
        for (int n = 0; n < 16; ++n) {
            float e = __expf(sacc[n][r] - m);
            sacc[n][r] = e;
            s += e;
        }
#pragma unroll
        for (int off = 1; off < 16; off <<= 1) s += __shfl_xor(s, off, 16);
        float inv = 1.f / s;
#pragma unroll
        for (int n = 0; n < 16; ++n) sacc[n][r] *= inv;
    }
    __syncthreads();

#pragma unroll
    for (int n = 0; n < 16; ++n)
#pragma unroll
        for (int r = 0; r < 4; ++r)
            g_s[(c + r) * 264 + n * 16 + lr] = f2bf(sacc[n][r]);

#pragma unroll
    for (int it = 0; it < 8; ++it) {
        int ti = it * 512 + tid;
        int x = ti >> 4, dg = ti & 15;
        int4 vv = make_int4(0, 0, 0, 0);
        if (x < 255)
            vv = *(const int4*)(qkv + (size_t)(ln * 128 + 1 + x) * QKVW_ + 2 * H_ + h * HD_ + dg * 8);
        const u16* vs = (const u16*)&vv;
#pragma unroll
        for (int i = 0; i < 8; ++i) {
            int d = dg * 8 + i;
            int sl = x >> 3, xo = x & 7;
            kv_s[d * 256 + (((sl ^ (d & 15)) << 3) + xo)] = vs[i];
        }
    }
    __syncthreads();

    f32x4 oacc[8];
#pragma unroll
    for (int n = 0; n < 8; ++n) oacc[n] = (f32x4){0.f, 0.f, 0.f, 0.f};
#pragma unroll
    for (int kk = 0; kk < 8; ++kk) {
        int prow = w * 16 + lr;
        bf16x8 pa = *(const bf16x8*)&g_s[prow * 264 + kk * 32 + lg * 8];
#pragma unroll
        for (int n = 0; n < 8; ++n) {
            int d = n * 16 + lr;
            int sl = kk * 4 + lg;
            bf16x8 vb = *(const bf16x8*)&kv_s[d * 256 + ((sl ^ (d & 15)) << 3)];
            oacc[n] = __builtin_amdgcn_mfma_f32_16x16x32_bf16(pa, vb, oacc[n], 0, 0, 0);
        }
    }

#pragma unroll
    for (int n = 0; n < 8; ++n)
#pragma unroll
        for (int r = 0; r < 4; ++r)
            attn_out[(size_t)(ln * 128 + c + r) * H_ + h * HD_ + n * 16 + lr] = f2bf(oacc[n][r]);
}

// ---------------------------------------------------------------------------
extern "C" void kernel_launch(void* const* d_in, const int* in_sizes, int n_in,
                              void* d_out, int out_size, void* d_ws, size_t ws_size,
                              hipStream_t stream)
{
    (void)in_sizes; (void)n_in; (void)out_size;

    const float* hs    = (const float*)d_in[0];
    const float* pos   = (const float*)d_in[1];
    const float* Wq    = (const float*)d_in[2];
    const float* Wk    = (const float*)d_in[3];
    const float* Wv    = (const float*)d_in[4];
    const float* Wrel  = (const float*)d_in[5];
    const float* Wpost = (const float*)d_in[6];
    const float* pds   = (const float*)d_in[7];
    float* out = (float*)d_out;

    const long long WW = (long long)H_ * H_;
    const long long POSN = 256LL * H_;
    const long long fixed_elems = (long long)QKVW_ * H_ + 2 * WW + 2 * POSN;

    int G = 0;
    const int cand[6] = {32, 16, 8, 4, 2, 1};
    for (int ci = 0; ci < 6; ++ci) {
        int g = cand[ci];
        long long seg_elems = (long long)(g + 1) * 128 * (H_ + QKVW_)
                            + (long long)g * 128 * H_;
        if ((fixed_elems + seg_elems) * 2 <= (long long)ws_size) { G = g; break; }
    }
    if (G == 0) return;

    u16* wqkvb  = (u16*)d_ws;
    u16* wpostb = wqkvb + (long long)QKVW_ * H_;
    u16* wrelb  = wpostb + WW;
    u16* posb   = wrelb + WW;
    u16* relkb  = posb + POSN;
    u16* hsb    = relkb + POSN;
    u16* qkvb   = hsb + (long long)(G + 1) * 128 * H_;
    u16* attb   = qkvb + (long long)(G + 1) * 128 * QKVW_;

    dim3 blk(256);
    const long long BIG = 1LL << 60;

    conv_bf16<<<dim3(WW / 1024), blk, 0, stream>>>(Wq, 0, wqkvb,          WW, 0, BIG, 1, pds, H_);
    conv_bf16<<<dim3(WW / 1024), blk, 0, stream>>>(Wk, 0, wqkvb + WW,     WW, 0, BIG, 2, nullptr, H_);
    conv_bf16<<<dim3(WW / 1024), blk, 0, stream>>>(Wv, 0, wqkvb + 2 * WW, WW, 0, BIG, 0, nullptr, H_);
    conv_bf16<<<dim3(WW / 1024), blk, 0, stream>>>(Wpost, 0, wpostb,      WW, 0, BIG, 0, nullptr, H_);
    conv_bf16<<<dim3(WW / 1024), blk, 0, stream>>>(Wrel, 0, wrelb,        WW, 0, BIG, 0, nullptr, H_);
    conv_bf16<<<dim3(POSN / 1024), blk, 0, stream>>>(pos, 0, posb, POSN, 0, 255LL * H_, 0, nullptr, H_);

    gemm_bt<1><<<dim3(H_ / 128, 2), blk, 0, stream>>>(posb, wrelb, relkb, 256, H_, H_, H_);

    for (int b = 0; b < B_; ++b) {
        for (int n0 = 0; n0 < NB_; n0 += G) {
            const int Mh = (G + 1) * 128;
            const long long hs_base = ((long long)b * S_ + (long long)(n0 - 1) * CHUNK_) * H_;
            const long long zb = (n0 == 0) ? (long long)CHUNK_ * H_ : 0;
            const long long hn = (long long)Mh * H_;

            conv_bf16<<<dim3(hn / 1024), blk, 0, stream>>>(hs, hs_base, hsb, hn, zb, BIG, 0, nullptr, H_);

            gemm_bt<1><<<dim3(QKVW_ / 128, Mh / 128), blk, 0, stream>>>(
                hsb, wqkvb, qkvb, Mh, QKVW_, H_, QKVW_);

            attn_mfma<<<dim3(G, NH_), dim3(512), 0, stream>>>(qkvb, relkb, attb);

            gemm_bt<0><<<dim3(H_ / 128, G), blk, 0, stream>>>(
                attb, wpostb, out + ((long long)b * S_ + (long long)n0 * CHUNK_) * H_,
                G * CHUNK_, H_, H_, H_);
        }
    }
}

// Round 7
// 715.527 us; speedup vs baseline: 10.3883x; 1.0198x over previous
//
#include <hip/hip_runtime.h>
#include <hip/hip_bf16.h>
#include <math.h>

// ---------------------------------------------------------------------------
// Gemma audio layer, round 6: kill the 8-way LDS bank conflict in the GEMM
// K-loop (XOR slot swizzle, pre-swizzled global_load_lds sources), revert the
// XCD swizzle (round 5: FETCH 80->206MB, no gain). Ring-4 + counted vmcnt +
// setprio kept from round 5. Attention/conv unchanged.
// ---------------------------------------------------------------------------

#define NH_    12
#define HD_    128
#define H_     1536
#define B_     4
#define S_     4096
#define CHUNK_ 128
#define CTX_   255
#define NB_    32
#define QKVW_  4608

typedef unsigned short u16;
typedef short bf16x8 __attribute__((ext_vector_type(8)));
typedef float f32x4 __attribute__((ext_vector_type(4)));

static constexpr float Q_SCALE_F = (float)(0.08838834764831845 / 0.6931471805599453);
static constexpr float K_SCALE_F = (float)(1.3132616875182228 / 0.6931471805599453);

__device__ __forceinline__ u16 f2bf(float f) {
    __hip_bfloat16 h = __float2bfloat16(f);
    return __builtin_bit_cast(u16, h);
}
__device__ __forceinline__ float bf2f(u16 u) {
    unsigned int t = ((unsigned int)u) << 16;
    return __builtin_bit_cast(float, t);
}

__device__ __forceinline__ void gload_lds16(const u16* src_global, u16* dst_lds) {
    __builtin_amdgcn_global_load_lds(
        (const __attribute__((address_space(1))) unsigned int*)src_global,
        (__attribute__((address_space(3))) unsigned int*)dst_lds,
        16, 0, 0);
}

// ---------------------------------------------------------------------------
// fp32 -> bf16 conversion with optional scaling / zero-fill.
// ---------------------------------------------------------------------------
__global__ __launch_bounds__(256)
void conv_bf16(const float* __restrict__ src, long long base,
               u16* __restrict__ dst, long long n,
               long long zero_below, long long zero_from,
               int mode, const float* __restrict__ pds, int ncols)
{
    long long i = ((long long)blockIdx.x * 256 + threadIdx.x) * 4;
    if (i >= n) return;
    float4 v = make_float4(0.f, 0.f, 0.f, 0.f);
    if (i >= zero_below && i < zero_from)
        v = *(const float4*)(src + base + i);
    float s = 1.f;
    if (mode == 1) {
        int row = (int)(i / ncols);
        float x = pds[row & 127];
        float sp = (x > 20.f) ? x : log1pf(__expf(x));
        s = Q_SCALE_F * sp;
    } else if (mode == 2) {
        s = K_SCALE_F;
    }
    ushort4 o = make_ushort4(f2bf(v.x * s), f2bf(v.y * s), f2bf(v.z * s), f2bf(v.w * s));
    *(ushort4*)(dst + i) = o;
}

// ---------------------------------------------------------------------------
// bf16 GEMM  C[M,N] = A[M,K] @ B[N,K]^T  (row-major bf16, K mult of 128,
// M,N mult of 128). OUTB: 1 -> bf16 C (LDS-staged coalesced stores), 0 -> fp32.
// 128x128 tile, 4 waves, 16x16x32 MFMA.
// LDS tile layout: [row][4 slots of 16B], physical slot = s ^ (row&3)
// (conflict-free ds_read_b128: 16 lanes sharing a k-slot spread 4 ways x 2
// row-parities = 2 lanes/bank = free). global_load_lds dests stay LINEAR;
// the global SOURCE is pre-swizzled (rule: both-sides-or-neither).
// K-loop: ring of 4 LDS buffers, stage 2 tiles ahead, ONE raw s_barrier and
// counted s_waitcnt vmcnt(8) per iter (T4); setprio around MFMA (T5).
// ---------------------------------------------------------------------------
#define STAGE(kt, bufc) do {                                                   \
    const int _ko = (kt) << 5;                                                 \
    gload_lds16(srcA[0] + _ko, lds + (bufc) * 4096 + pbase[0]);                \
    gload_lds16(srcA[1] + _ko, lds + (bufc) * 4096 + pbase[1]);                \
    gload_lds16(srcB[0] + _ko, lds + 16384 + (bufc) * 4096 + pbase[0]);        \
    gload_lds16(srcB[1] + _ko, lds + 16384 + (bufc) * 4096 + pbase[1]);        \
} while (0)

#define ITER(t, b) do {                                                        \
    if ((t) + 2 < nk) {                                                        \
        STAGE((t) + 2, ((b) + 2) & 3);                                         \
        asm volatile("s_waitcnt vmcnt(8)" ::: "memory");                       \
    } else if ((t) + 1 < nk) {                                                 \
        asm volatile("s_waitcnt vmcnt(4)" ::: "memory");                       \
    } else {                                                                   \
        asm volatile("s_waitcnt vmcnt(0)" ::: "memory");                       \
    }                                                                          \
    __builtin_amdgcn_s_barrier();                                              \
    asm volatile("" ::: "memory");                                            \
    bf16x8 af[4], bfr[4];                                                      \
    _Pragma("unroll")                                                          \
    for (int m = 0; m < 4; ++m)                                                \
        af[m] = *(const bf16x8*)&lds[(b) * 4096 + (wr + m * 16 + lr) * 32 + sw8]; \
    _Pragma("unroll")                                                          \
    for (int n = 0; n < 4; ++n)                                                \
        bfr[n] = *(const bf16x8*)&lds[16384 + (b) * 4096 + (wc + n * 16 + lr) * 32 + sw8]; \
    __builtin_amdgcn_s_setprio(1);                                             \
    _Pragma("unroll")                                                          \
    for (int m = 0; m < 4; ++m)                                                \
        _Pragma("unroll")                                                      \
        for (int n = 0; n < 4; ++n)                                            \
            acc[m][n] = __builtin_amdgcn_mfma_f32_16x16x32_bf16(af[m], bfr[n], acc[m][n], 0, 0, 0); \
    __builtin_amdgcn_s_setprio(0);                                             \
} while (0)

template<int OUTB>
__global__ __launch_bounds__(256)
void gemm_bt(const u16* __restrict__ A, const u16* __restrict__ B,
             void* __restrict__ Cp, int M, int N, int K, int ldc)
{
    // 64 KB: A ring 4x8KB at [0..16384) u16, B ring 4x8KB at [16384..32768).
    // Epilogue cbuf aliases lds[0..8704) -- disjoint from last-read buf 3.
    __shared__ __align__(16) u16 lds[32768];

    const int tid = threadIdx.x;
    const int w = tid >> 6, l = tid & 63;
    const int lr = l & 15, lg = l >> 4;
    const int bm = blockIdx.y * 128, bn = blockIdx.x * 128;
    const int wr = (w >> 1) * 64, wc = (w & 1) * 64;

    // fragment-read swizzled slot (per-lane constant): slot = lg ^ (lr&3)
    const int sw8 = (lg ^ (lr & 3)) * 8;

    // staging: chunk c in {0,1}: linear 16B slot p = (w*2+c)*64 + l in tile;
    // dest row = p>>2, dest phys slot = p&3; SOURCE uses logical slot
    // s_log = (p&3) ^ (row&3) so that LDS content is swizzle-consistent.
    const u16* srcA[2];
    const u16* srcB[2];
    int pbase[2];
#pragma unroll
    for (int c = 0; c < 2; ++c) {
        const int p = (w * 2 + c) * 64 + l;
        const int row = p >> 2;
        const int s_log = (p & 3) ^ (row & 3);
        pbase[c] = p * 8;                     // linear u16 dest offset in tile
        srcA[c] = A + (size_t)(bm + row) * K + s_log * 8;
        srcB[c] = B + (size_t)(bn + row) * K + s_log * 8;
    }

    f32x4 acc[4][4];
#pragma unroll
    for (int m = 0; m < 4; ++m)
#pragma unroll
        for (int n = 0; n < 4; ++n) acc[m][n] = (f32x4){0.f, 0.f, 0.f, 0.f};

    const int nk = K >> 5;                    // K/32; K%128==0 -> nk%4==0
    STAGE(0, 0);
    STAGE(1, 1);
    for (int t0 = 0; t0 < nk; t0 += 4) {
        ITER(t0 + 0, 0);
        ITER(t0 + 1, 1);
        ITER(t0 + 2, 2);
        ITER(t0 + 3, 3);
    }

    // C/D layout: col = lane&15 (lr), row = lg*4 + r
    if (OUTB) {
        // coalesced epilogue via LDS: halves of 64 rows, stride 136 u16
#pragma unroll
        for (int h = 0; h < 2; ++h) {
            if (wr == h * 64) {
#pragma unroll
                for (int m = 0; m < 4; ++m)
#pragma unroll
                    for (int n = 0; n < 4; ++n)
#pragma unroll
                        for (int r = 0; r < 4; ++r)
                            lds[(m * 16 + lg * 4 + r) * 136 + wc + n * 16 + lr] =
                                f2bf(acc[m][n][r]);
            }
            __syncthreads();
#pragma unroll
            for (int it = 0; it < 4; ++it) {
                const int sid = it * 256 + tid;
                const int row = sid >> 4, sl = sid & 15;
                int4 val = *(const int4*)&lds[row * 136 + sl * 8];
                *(int4*)((u16*)Cp + (size_t)(bm + h * 64 + row) * ldc + bn + sl * 8) = val;
            }
            __syncthreads();
        }
    } else {
#pragma unroll
        for (int m = 0; m < 4; ++m)
#pragma unroll
            for (int n = 0; n < 4; ++n)
#pragma unroll
                for (int r = 0; r < 4; ++r) {
                    const int row = bm + wr + m * 16 + lg * 4 + r;
                    const int col = bn + wc + n * 16 + lr;
                    ((float*)Cp)[(size_t)row * ldc + col] = acc[m][n][r];
                }
    }
}

// ---------------------------------------------------------------------------
// MFMA attention (unchanged from round 2/4/5).
// ---------------------------------------------------------------------------
__global__ __launch_bounds__(512)
void attn_mfma(const u16* __restrict__ qkv, const u16* __restrict__ relk,
               u16* __restrict__ attn_out)
{
    __shared__ __align__(16) u16 kv_s[256 * 128];   // relk -> k_ctx -> V^T
    __shared__ __align__(16) u16 g_s[128 * 264];    // G -> P

    const int ln = blockIdx.x, h = blockIdx.y;
    const int tid = threadIdx.x;
    const int w = tid >> 6, l = tid & 63;
    const int lr = l & 15, lg = l >> 4;
    const size_t qrow0 = (size_t)(ln + 1) * 128;

    bf16x8 qa[4];
    {
        const u16* qp = qkv + (qrow0 + w * 16 + lr) * QKVW_ + h * HD_ + lg * 8;
#pragma unroll
        for (int kk = 0; kk < 4; ++kk) qa[kk] = *(const bf16x8*)(qp + kk * 32);
    }

#pragma unroll
    for (int it = 0; it < 8; ++it) {
        int sid = it * 512 + tid;
        int row = sid >> 4, sl = sid & 15;
        int4 v = *(const int4*)(relk + (size_t)row * H_ + h * HD_ + sl * 8);
        *(int4*)&kv_s[row * 128 + (((sl ^ (row & 15)) << 3))] = v;
    }
    __syncthreads();

    f32x4 sacc[16];
#pragma unroll
    for (int n = 0; n < 16; ++n) sacc[n] = (f32x4){0.f, 0.f, 0.f, 0.f};
#pragma unroll
    for (int n = 0; n < 16; ++n)
#pragma unroll
        for (int kk = 0; kk < 4; ++kk) {
            int row = n * 16 + lr;
            int sl = kk * 4 + lg;
            bf16x8 bfrag = *(const bf16x8*)&kv_s[row * 128 + ((sl ^ (row & 15)) << 3)];
            sacc[n] = __builtin_amdgcn_mfma_f32_16x16x32_bf16(qa[kk], bfrag, sacc[n], 0, 0, 0);
        }

    const int c = w * 16 + lg * 4;
#pragma unroll
    for (int n = 0; n < 16; ++n)
#pragma unroll
        for (int r = 0; r < 4; ++r)
            g_s[(c + r) * 264 + n * 16 + lr] = f2bf(sacc[n][r]);
    __syncthreads();

#pragma unroll
    for (int it = 0; it < 8; ++it) {
        int sid = it * 512 + tid;
        int row = sid >> 4, sl = sid & 15;
        int4 v = make_int4(0, 0, 0, 0);
        if (row < 255)
            v = *(const int4*)(qkv + (size_t)(ln * 128 + 1 + row) * QKVW_ + H_ + h * HD_ + sl * 8);
        *(int4*)&kv_s[row * 128 + ((sl ^ (row & 15)) << 3)] = v;
    }
    __syncthreads();

#pragma unroll
    for (int n = 0; n < 16; ++n) sacc[n] = (f32x4){0.f, 0.f, 0.f, 0.f};
#pragma unroll
    for (int n = 0; n < 16; ++n)
#pragma unroll
        for (int kk = 0; kk < 4; ++kk) {
            int row = n * 16 + lr;
            int sl = kk * 4 + lg;
            bf16x8 bfrag = *(const bf16x8*)&kv_s[row * 128 + ((sl ^ (row & 15)) << 3)];
            sacc[n] = __builtin_amdgcn_mfma_f32_16x16x32_bf16(qa[kk], bfrag, sacc[n], 0, 0, 0);
        }

#pragma unroll
    for (int n = 0; n < 16; ++n)
#pragma unroll
        for (int r = 0; r < 4; ++r) {
            int cc = c + r;
            int x = n * 16 + lr;
            float val;
            if (x == 255) {
                val = -1e30f;
            } else {
                int dx = x - cc;
                u16 bdu = (dx >= 0) ? g_s[cc * 264 + dx]
                                    : g_s[(cc - 1) * 264 + dx + 256];
                float t = (sacc[n][r] + bf2f(bdu)) * (1.f / 50.f);
                val = 50.f * tanhf(t);
            }
            sacc[n][r] = val;
        }

#pragma unroll
    for (int r = 0; r < 4; ++r) {
        float m = -1e30f;
#pragma unroll
        for (int n = 0; n < 16; ++n) m = fmaxf(m, sacc[n][r]);
#pragma unroll
        for (int off = 1; off < 16; off <<= 1) m = fmaxf(m, __shfl_xor(m, off, 16));
        float s = 0.f;
#pragma unroll
        for (int n = 0; n < 16; ++n) {
            float e = __expf(sacc[n][r] - m);
            sacc[n][r] = e;
            s += e;
        }
#pragma unroll
        for (int off = 1; off < 16; off <<= 1) s += __shfl_xor(s, off, 16);
        float inv = 1.f / s;
#pragma unroll
        for (int n = 0; n < 16; ++n) sacc[n][r] *= inv;
    }
    __syncthreads();

#pragma unroll
    for (int n = 0; n < 16; ++n)
#pragma unroll
        for (int r = 0; r < 4; ++r)
            g_s[(c + r) * 264 + n * 16 + lr] = f2bf(sacc[n][r]);

#pragma unroll
    for (int it = 0; it < 8; ++it) {
        int ti = it * 512 + tid;
        int x = ti >> 4, dg = ti & 15;
        int4 vv = make_int4(0, 0, 0, 0);
        if (x < 255)
            vv = *(const int4*)(qkv + (size_t)(ln * 128 + 1 + x) * QKVW_ + 2 * H_ + h * HD_ + dg * 8);
        const u16* vs = (const u16*)&vv;
#pragma unroll
        for (int i = 0; i < 8; ++i) {
            int d = dg * 8 + i;
            int sl = x >> 3, xo = x & 7;
            kv_s[d * 256 + (((sl ^ (d & 15)) << 3) + xo)] = vs[i];
        }
    }
    __syncthreads();

    f32x4 oacc[8];
#pragma unroll
    for (int n = 0; n < 8; ++n) oacc[n] = (f32x4){0.f, 0.f, 0.f, 0.f};
#pragma unroll
    for (int kk = 0; kk < 8; ++kk) {
        int prow = w * 16 + lr;
        bf16x8 pa = *(const bf16x8*)&g_s[prow * 264 + kk * 32 + lg * 8];
#pragma unroll
        for (int n = 0; n < 8; ++n) {
            int d = n * 16 + lr;
            int sl = kk * 4 + lg;
            bf16x8 vb = *(const bf16x8*)&kv_s[d * 256 + ((sl ^ (d & 15)) << 3)];
            oacc[n] = __builtin_amdgcn_mfma_f32_16x16x32_bf16(pa, vb, oacc[n], 0, 0, 0);
        }
    }

#pragma unroll
    for (int n = 0; n < 8; ++n)
#pragma unroll
        for (int r = 0; r < 4; ++r)
            attn_out[(size_t)(ln * 128 + c + r) * H_ + h * HD_ + n * 16 + lr] = f2bf(oacc[n][r]);
}

// ---------------------------------------------------------------------------
extern "C" void kernel_launch(void* const* d_in, const int* in_sizes, int n_in,
                              void* d_out, int out_size, void* d_ws, size_t ws_size,
                              hipStream_t stream)
{
    (void)in_sizes; (void)n_in; (void)out_size;

    const float* hs    = (const float*)d_in[0];
    const float* pos   = (const float*)d_in[1];
    const float* Wq    = (const float*)d_in[2];
    const float* Wk    = (const float*)d_in[3];
    const float* Wv    = (const float*)d_in[4];
    const float* Wrel  = (const float*)d_in[5];
    const float* Wpost = (const float*)d_in[6];
    const float* pds   = (const float*)d_in[7];
    float* out = (float*)d_out;

    const long long WW = (long long)H_ * H_;
    const long long POSN = 256LL * H_;
    const long long fixed_elems = (long long)QKVW_ * H_ + 2 * WW + 2 * POSN;

    int G = 0;
    const int cand[6] = {32, 16, 8, 4, 2, 1};
    for (int ci = 0; ci < 6; ++ci) {
        int g = cand[ci];
        long long seg_elems = (long long)(g + 1) * 128 * (H_ + QKVW_)
                            + (long long)g * 128 * H_;
        if ((fixed_elems + seg_elems) * 2 <= (long long)ws_size) { G = g; break; }
    }
    if (G == 0) return;

    u16* wqkvb  = (u16*)d_ws;
    u16* wpostb = wqkvb + (long long)QKVW_ * H_;
    u16* wrelb  = wpostb + WW;
    u16* posb   = wrelb + WW;
    u16* relkb  = posb + POSN;
    u16* hsb    = relkb + POSN;
    u16* qkvb   = hsb + (long long)(G + 1) * 128 * H_;
    u16* attb   = qkvb + (long long)(G + 1) * 128 * QKVW_;

    dim3 blk(256);
    const long long BIG = 1LL << 60;

    conv_bf16<<<dim3(WW / 1024), blk, 0, stream>>>(Wq, 0, wqkvb,          WW, 0, BIG, 1, pds, H_);
    conv_bf16<<<dim3(WW / 1024), blk, 0, stream>>>(Wk, 0, wqkvb + WW,     WW, 0, BIG, 2, nullptr, H_);
    conv_bf16<<<dim3(WW / 1024), blk, 0, stream>>>(Wv, 0, wqkvb + 2 * WW, WW, 0, BIG, 0, nullptr, H_);
    conv_bf16<<<dim3(WW / 1024), blk, 0, stream>>>(Wpost, 0, wpostb,      WW, 0, BIG, 0, nullptr, H_);
    conv_bf16<<<dim3(WW / 1024), blk, 0, stream>>>(Wrel, 0, wrelb,        WW, 0, BIG, 0, nullptr, H_);
    conv_bf16<<<dim3(POSN / 1024), blk, 0, stream>>>(pos, 0, posb, POSN, 0, 255LL * H_, 0, nullptr, H_);

    gemm_bt<1><<<dim3(H_ / 128, 2), blk, 0, stream>>>(posb, wrelb, relkb, 256, H_, H_, H_);

    for (int b = 0; b < B_; ++b) {
        for (int n0 = 0; n0 < NB_; n0 += G) {
            const int Mh = (G + 1) * 128;
            const long long hs_base = ((long long)b * S_ + (long long)(n0 - 1) * CHUNK_) * H_;
            const long long zb = (n0 == 0) ? (long long)CHUNK_ * H_ : 0;
            const long long hn = (long long)Mh * H_;

            conv_bf16<<<dim3(hn / 1024), blk, 0, stream>>>(hs, hs_base, hsb, hn, zb, BIG, 0, nullptr, H_);

            gemm_bt<1><<<dim3(QKVW_ / 128, Mh / 128), blk, 0, stream>>>(
                hsb, wqkvb, qkvb, Mh, QKVW_, H_, QKVW_);

            attn_mfma<<<dim3(G, NH_), dim3(512), 0, stream>>>(qkvb, relkb, attb);

            gemm_bt<0><<<dim3(H_ / 128, G), blk, 0, stream>>>(
                attb, wpostb, out + ((long long)b * S_ + (long long)n0 * CHUNK_) * H_,
                G * CHUNK_, H_, H_, H_);
        }
    }
}